// Round 8
// baseline (288.853 us; speedup 1.0000x reference)
//
#include <hip/hip_runtime.h>

// SSIM (window=8 box sums) over 96 images of 512x512 fp32.
// v8: NO LDS in the hot loop. After 7 rounds the invariant across every
// ~95 us variant (barrier or barrier-free) was the per-row LDS exchange
// (~23 us of DS-pipe time, dependency-coupled to everything). Here each
// thread loads its own horizontal halo redundantly from global (3
// overlapping b128 per image per row; L1 serves the overlap) and computes
// the horizontal 8-sums in registers. The vertical ring stores the
// horizontally-summed quantities (4q x 4outputs x 8 rows = 128 VGPRs), so
// the vertical slide is 32 scalar ops. Zero DS ops, zero fences, zero
// barriers -> waves fully independent -> HBM can saturate.
//  - depth-2 prefetch (parity-indexed), consume-then-issue
//  - __launch_bounds__(128,1): do NOT force min-waves (v3/v4 lesson: forced
//    caps make the allocator spill; v7 showed natural allocation stays lean)
//  - halo loads clamped to col 508 so nothing reads past the row; outputs
//    needing clamped garbage are exactly the predicated-out ones

#define W 512
#define OW 505
#define OH 505
#define TH 16
#define NSTRIP ((OH + TH - 1) / TH)   // 32
#define NIMG 96
#define NPIX (96.0 * 505.0 * 505.0)   // 24482400

__device__ __forceinline__ float4 ld4(const float* p) { return *(const float4*)p; }

__global__ void finalize(const double* p, float* out) {
    out[0] = 1.0f - (float)(*p / NPIX);
}

__global__ void __launch_bounds__(128, 1)
ssim_main(const float* __restrict__ gt, const float* __restrict__ ni,
          double* __restrict__ acc_out)
{
    const int t   = threadIdx.x;      // 0..127
    const int c0  = t * 4;            // output cols c0..c0+3
    const int c4  = (c0 + 4 < 508) ? c0 + 4 : 508;   // clamped halo bases
    const int c8  = (c0 + 8 < 508) ? c0 + 8 : 508;
    const int img = blockIdx.y;
    const int R0  = blockIdx.x * TH;  // first output row (mult of 16)
    const int R1  = min(R0 + TH, OH);

    const float C1 = 1e-4f, C2 = 9e-4f;

    const float* gx = gt + (size_t)img * (W * W);
    const float* gy = ni + (size_t)img * (W * W);

    __shared__ float wpart[2];        // final reduce only — not in hot loop

    // ring of horizontal sums per input row: [quantity][slot][4 outputs]
    float rgx[8][4], rgy[8][4], rgq[8][4], rgp[8][4];
    float vsx[4], vsy[4], vsq[4], vsp[4];
#pragma unroll
    for (int j = 0; j < 4; ++j) { vsx[j]=0.f; vsy[j]=0.f; vsq[j]=0.f; vsp[j]=0.f; }

    float4 pf[2][6];   // [parity][xa,xb,xc, ya,yb,yc]

#define ISSUE(pp, row) {                                                  \
        const float* bx_ = gx + (size_t)(row) * W;                        \
        const float* by_ = gy + (size_t)(row) * W;                        \
        pf[pp][0] = ld4(bx_ + c0); pf[pp][1] = ld4(bx_ + c4);             \
        pf[pp][2] = ld4(bx_ + c8);                                        \
        pf[pp][3] = ld4(by_ + c0); pf[pp][4] = ld4(by_ + c4);             \
        pf[pp][5] = ld4(by_ + c8);                                        \
    }

// 8-window sliding sums over v[0..10] -> Hd[0..3]
#define HS(Hd, v) {                                                       \
        float s_ = ((v[0]+v[1])+(v[2]+v[3])) + ((v[4]+v[5])+(v[6]+v[7])); \
        Hd[0] = s_;                                                       \
        s_ += v[8]  - v[0]; Hd[1] = s_;                                   \
        s_ += v[9]  - v[1]; Hd[2] = s_;                                   \
        s_ += v[10] - v[2]; Hd[3] = s_;                                   \
    }

// consume prefetch parity pp -> horizontal sums of the 4 quantities
#define COMPH(pp, Hx, Hy, Hq, Hp) {                                       \
        float x_[12], y_[12];                                             \
        *(float4*)&x_[0] = pf[pp][0]; *(float4*)&x_[4] = pf[pp][1];       \
        *(float4*)&x_[8] = pf[pp][2];                                     \
        *(float4*)&y_[0] = pf[pp][3]; *(float4*)&y_[4] = pf[pp][4];       \
        *(float4*)&y_[8] = pf[pp][5];                                     \
        float q_[11], p_[11];                                             \
        _Pragma("unroll") for (int i = 0; i < 11; ++i) {                  \
            q_[i] = x_[i]*x_[i] + y_[i]*y_[i];                            \
            p_[i] = x_[i]*y_[i];                                          \
        }                                                                 \
        HS(Hx, x_) HS(Hy, y_) HS(Hq, q_) HS(Hp, p_)                       \
    }

// warm-up row k (0..6): input row R0+k from parity k&1; refill with row R0+k+2
#define WARM(k) {                                                         \
        float Hx[4], Hy[4], Hq[4], Hp[4];                                 \
        COMPH((k)&1, Hx, Hy, Hq, Hp)                                      \
        ISSUE((k)&1, R0 + (k) + 2)                                        \
        _Pragma("unroll") for (int j = 0; j < 4; ++j) {                   \
            rgx[k][j]=Hx[j]; rgy[k][j]=Hy[j];                             \
            rgq[k][j]=Hq[j]; rgp[k][j]=Hp[j];                             \
            vsx[j]+=Hx[j]; vsy[j]+=Hy[j]; vsq[j]+=Hq[j]; vsp[j]+=Hp[j];   \
        }                                                                 \
    }

// steady row: output r_ = rbase+k; consumes input row r_+7 (parity (k+1)&1);
// ring slot holds row r_-1's H (zero for the very first output row)
#define ROWB(k, slot) {                                                   \
        const int r_ = rbase + (k);                                       \
        if (r_ < R1) { /* block-uniform */                                \
            float Hx[4], Hy[4], Hq[4], Hp[4];                             \
            COMPH(((k)+1)&1, Hx, Hy, Hq, Hp)                              \
            if (r_ + 2 < R1) ISSUE(((k)+1)&1, r_ + 9)                     \
            _Pragma("unroll") for (int j = 0; j < 4; ++j) {               \
                vsx[j] += Hx[j] - rgx[slot][j]; rgx[slot][j] = Hx[j];     \
                vsy[j] += Hy[j] - rgy[slot][j]; rgy[slot][j] = Hy[j];     \
                vsq[j] += Hq[j] - rgq[slot][j]; rgq[slot][j] = Hq[j];     \
                vsp[j] += Hp[j] - rgp[slot][j]; rgp[slot][j] = Hp[j];     \
            }                                                             \
            _Pragma("unroll") for (int j = 0; j < 4; ++j) {               \
                float Sx = vsx[j], Sy = vsy[j];                           \
                float Sq = vsq[j], Sp = vsp[j];                           \
                float mu12 = Sx * Sy;                                     \
                float n1v = 2.0f * mu12 + C1;                             \
                float n2v = 2.0f * (Sp - mu12) + C2;                      \
                float sx2 = Sx * Sx, sy2 = Sy * Sy;                       \
                float d1  = sx2 + sy2 + C1;                               \
                float d2  = (Sq - sx2 - sy2) + C2;                        \
                float sv  = (n1v * n2v) * __builtin_amdgcn_rcpf(d1 * d2); \
                if (c0 + j < OW) acc += sv;                               \
            }                                                             \
        }                                                                 \
    }

    // prime the pipeline: rows R0, R0+1
    ISSUE(0, R0)
    ISSUE(1, R0 + 1)

    // warm-up: rows R0..R0+6 -> ring slots 0..6 (each refills with row +2;
    // after WARM(6), parity0 holds R0+8, parity1 holds R0+7)
    WARM(0) WARM(1) WARM(2) WARM(3) WARM(4) WARM(5) WARM(6)
#pragma unroll
    for (int j = 0; j < 4; ++j) {     // slot 7 = zeros (nothing leaves at r=R0)
        rgx[7][j]=0.f; rgy[7][j]=0.f; rgq[7][j]=0.f; rgp[7][j]=0.f;
    }

    float acc = 0.0f;

    // output row ka = r-R0 subtracts row R0+ka-1 = ring slot (ka+7)&7
    for (int rbase = R0; rbase < R1; rbase += 8) {
        ROWB(0, 7)
        ROWB(1, 0)
        ROWB(2, 1)
        ROWB(3, 2)
        ROWB(4, 3)
        ROWB(5, 4)
        ROWB(6, 5)
        ROWB(7, 6)
    }

    // reduction: wave shuffle -> LDS -> one double atomic per block
#pragma unroll
    for (int off = 32; off > 0; off >>= 1) acc += __shfl_down(acc, off);
    const int wave = t >> 6, lane = t & 63;
    if (lane == 0) wpart[wave] = acc;
    __syncthreads();
    if (t == 0) atomicAdd(acc_out, (double)(wpart[0] + wpart[1]));
}

extern "C" void kernel_launch(void* const* d_in, const int* in_sizes, int n_in,
                              void* d_out, int out_size, void* d_ws, size_t ws_size,
                              hipStream_t stream) {
    const float* gt = (const float*)d_in[0];
    const float* ni = (const float*)d_in[1];
    double* acc = (double*)d_ws;   // 8 bytes scratch, re-poisoned every call

    hipMemsetAsync(acc, 0, sizeof(double), stream);
    dim3 grid(NSTRIP, NIMG);
    ssim_main<<<grid, 128, 0, stream>>>(gt, ni, acc);
    finalize<<<1, 1, 0, stream>>>(acc, (float*)d_out);
}